// Round 4
// baseline (209.765 us; speedup 1.0000x reference)
//
#include <hip/hip_runtime.h>

typedef __bf16 bf16x8 __attribute__((ext_vector_type(8)));
typedef float f32x4 __attribute__((ext_vector_type(4)));
typedef float f32x16 __attribute__((ext_vector_type(16)));

#define MFMA16(a, b, c) __builtin_amdgcn_mfma_f32_16x16x32_bf16(a, b, c, 0, 0, 0)
#define MFMA32(a, b, c) __builtin_amdgcn_mfma_f32_32x32x16_bf16(a, b, c, 0, 0, 0)
#define GLDS16(g, l)                                                              \
  __builtin_amdgcn_global_load_lds((const __attribute__((address_space(1))) void*)(g), \
                                   (__attribute__((address_space(3))) void*)(l), 16, 0, 0)

// ---------------- convert f32 -> bf16 (straight) ----------------
__global__ __launch_bounds__(256) void cvt_bf16_kernel(const float* __restrict__ in,
                                                       __bf16* __restrict__ out, int n4) {
  int i = blockIdx.x * 256 + threadIdx.x;
  if (i < n4) {
    float4 v = ((const float4*)in)[i];
    union { __bf16 b[4]; uint2 u; } t;
    t.b[0] = (__bf16)v.x; t.b[1] = (__bf16)v.y;
    t.b[2] = (__bf16)v.z; t.b[3] = (__bf16)v.w;
    ((uint2*)out)[i] = t.u;
  }
}

// ---------------- transpose-convert both weights in one launch ----------------
__global__ __launch_bounds__(256) void transpose_w_kernel(const float* __restrict__ Wq,
                                                          __bf16* __restrict__ WqT,
                                                          const float* __restrict__ Wo,
                                                          __bf16* __restrict__ WoT) {
  const int Kd = 1024;
  int bx = blockIdx.x;
  const float* W; __bf16* WT; int Nd, n0;
  if (bx < 96) { W = Wq; WT = WqT; Nd = 3072; n0 = bx * 32; }
  else         { W = Wo; WT = WoT; Nd = 1024; n0 = (bx - 96) * 32; }
  __shared__ float tile[32][33];
  int k0 = blockIdx.y * 32;
  int tid = threadIdx.x;
  int kk = tid >> 3, nn = (tid & 7) * 4;
  float4 v = *(const float4*)&W[(size_t)(k0 + kk) * Nd + n0 + nn];
  tile[kk][nn] = v.x; tile[kk][nn + 1] = v.y;
  tile[kk][nn + 2] = v.z; tile[kk][nn + 3] = v.w;
  __syncthreads();
  int n2 = tid >> 3, k2 = (tid & 7) * 4;
  union { __bf16 b[4]; uint2 u; } t;
  t.b[0] = (__bf16)tile[k2][n2];
  t.b[1] = (__bf16)tile[k2 + 1][n2];
  t.b[2] = (__bf16)tile[k2 + 2][n2];
  t.b[3] = (__bf16)tile[k2 + 3][n2];
  *(uint2*)&WT[(size_t)(n0 + n2) * Kd + k0 + k2] = t.u;
}

// ---------------- GEMM: C[M,N] = A[M,1024] @ BT[N,1024]^T + bias ----------------
template <bool OUT_F32, int NT>
__global__ __launch_bounds__(256) void gemm_kernel(const __bf16* __restrict__ A,
                                                   const __bf16* __restrict__ BT,
                                                   const float* __restrict__ bias,
                                                   void* __restrict__ Cout, int N,
                                                   int qn, float qs) {
  const int K = 1024;
  const int NJ = NT / 32;
  __shared__ __align__(16) __bf16 As[128 * 32];
  __shared__ __align__(16) __bf16 Bs[NT * 32];
  int tid = threadIdx.x;
  int wave = tid >> 6, lane = tid & 63;
  int quad = lane >> 4, l16 = lane & 15;
  int m0 = blockIdx.x * 128, n0 = blockIdx.y * NT;
  int wm = (wave >> 1) * 64, wn = (wave & 1) * (NT / 2);

  int srow = tid >> 2, scol = (tid & 3) * 8;
  const __bf16* aptr = A + (size_t)(m0 + srow) * K + scol;
  const __bf16* bptr = BT + (size_t)(n0 + srow) * K + scol;
  __bf16* asl = &As[(size_t)wave * 512];
  __bf16* bsl = &Bs[(size_t)wave * 512];

  f32x4 acc[4][NJ] = {};
  for (int k0 = 0; k0 < K; k0 += 32) {
    GLDS16(aptr + k0, asl);
    GLDS16(aptr + (size_t)64 * K + k0, asl + 2048);
    GLDS16(bptr + k0, bsl);
    if (NT == 128) GLDS16(bptr + (size_t)64 * K + k0, bsl + 2048);
    __syncthreads();
    bf16x8 af[4], bf[NJ];
    for (int i = 0; i < 4; i++)
      af[i] = *(bf16x8*)&As[(wm + i * 16 + l16) * 32 + quad * 8];
    for (int j = 0; j < NJ; j++)
      bf[j] = *(bf16x8*)&Bs[(wn + j * 16 + l16) * 32 + quad * 8];
    for (int i = 0; i < 4; i++)
      for (int j = 0; j < NJ; j++)
        acc[i][j] = MFMA16(af[i], bf[j], acc[i][j]);
    __syncthreads();
  }
  for (int j = 0; j < NJ; j++) {
    int col = n0 + wn + j * 16 + l16;
    float bv = bias[col];
    float sc = (col < qn) ? qs : 1.0f;
    for (int i = 0; i < 4; i++) {
      int rowb = m0 + wm + i * 16 + quad * 4;
      for (int r = 0; r < 4; r++) {
        float v = (acc[i][j][r] + bv) * sc;
        if (OUT_F32)
          ((float*)Cout)[(size_t)(rowb + r) * N + col] = v;
        else
          ((__bf16*)Cout)[(size_t)(rowb + r) * N + col] = (__bf16)v;
      }
    }
  }
}

// ---------------- transpose V slice of qkv -> Vt [b][h][d][t] ----------------
__global__ __launch_bounds__(256) void transpose_v_kernel(const __bf16* __restrict__ qkv,
                                                          __bf16* __restrict__ Vt) {
  const int T = 2048, C3 = 3072;
  __shared__ __align__(16) __bf16 tile[64][72];
  int t0 = blockIdx.x * 64;
  int h = blockIdx.y, b = blockIdx.z;
  int tid = threadIdx.x;
  int tt = tid >> 2, c = (tid & 3) * 16;
  const __bf16* src = qkv + (size_t)(b * T + t0 + tt) * C3 + 2048 + h * 64 + c;
  *(uint4*)&tile[tt][c] = *(const uint4*)src;
  *(uint4*)&tile[tt][c + 8] = *(const uint4*)(src + 8);
  __syncthreads();
  int dd = tid >> 2, t2 = (tid & 3) * 16;
  union { __bf16 b_[16]; uint4 u[2]; } o;
  for (int i = 0; i < 16; i++) o.b_[i] = tile[t2 + i][dd];
  __bf16* dst = Vt + ((size_t)(b * 16 + h) * 64 + dd) * T + t0 + t2;
  *(uint4*)dst = o.u[0];
  *(uint4*)(dst + 8) = o.u[1];
}

// ---------------- flash attention v4: 32x32x16 MFMA, frag-order LDS ----------------
// grid (32 q-tiles of 64, 16 heads, 2 batch), 128 thr = 2 waves x 32 q-rows.
// KV tile 64. LDS holds K/V in MFMA-fragment order (addr = base + lane*16 + imm):
// zero inner-loop address VALU, conflict-free reads, GLDS-identity staging.
// Double-buffered staging: 1 barrier/tile. No-max softmax (Q pre-scaled in GEMM1).
__global__ __launch_bounds__(128) void attn_kernel(const __bf16* __restrict__ qkv,
                                                   const __bf16* __restrict__ Vt,
                                                   __bf16* __restrict__ O) {
  const int T = 2048, C3 = 3072;
  int q0 = blockIdx.x * 64;
  int h = blockIdx.y, b = blockIdx.z;
  int tid = threadIdx.x, wave = tid >> 6, lane = tid & 63;
  int l31 = lane & 31, hw = lane >> 5;

  // KV[buf]: K frags (ct*4+c)*512, V frags 4096 + (kc*2+dt)*512  (elems)
  __shared__ __align__(16) __bf16 KV[2][8192];
  __shared__ __align__(16) __bf16 Ps[2][2048];  // per-wave P, frag-order + rh-XOR

  // Q A-frags: A[m=l31][k=hw*8+j], 4 d-chunks of 16
  const __bf16* qp = qkv + (size_t)(b * T + q0 + wave * 32 + l31) * C3 + h * 64 + hw * 8;
  bf16x8 aq[4];
  for (int c = 0; c < 4; c++) aq[c] = *(const bf16x8*)(qp + c * 16);

  const __bf16* kbase = qkv + (size_t)(b * T) * C3 + 1024 + h * 64;
  const __bf16* vbase = Vt + (size_t)(b * 16 + h) * 64 * T;

  // staging per-lane source bases (wave0 stages K, wave1 stages V)
  const __bf16* ksrc = kbase + (size_t)l31 * C3 + hw * 8;
  const __bf16* vsrc = vbase + (size_t)l31 * T + hw * 8;

  // P writer base (elems): kchi*512 + rh*256 + (hw^rh)*32 + jj  (+ ct*1024 + dq*8)
  int kchi = (lane >> 4) & 1, rh = (lane >> 3) & 1, jj = lane & 7;
  int wbase = kchi * 512 + rh * 256 + (hw ^ rh) * 32 + jj;
  // P reader base (elems): hw*256 + (l31 ^ 4hw)*8  (+ kc*512)
  int rbase = hw * 256 + (l31 ^ (hw * 4)) * 8;

  f32x16 o0 = {}, o1 = {}, ls = {};
  bf16x8 ones;
  for (int i = 0; i < 8; i++) ones[i] = (__bf16)1.0f;

  // prologue: stage tile 0 into buf 0
  if (wave == 0) {
    for (int ct = 0; ct < 2; ct++)
      for (int c = 0; c < 4; c++)
        GLDS16(ksrc + (size_t)ct * 32 * C3 + c * 16, &KV[0][(ct * 4 + c) * 512]);
  } else {
    for (int kc = 0; kc < 4; kc++)
      for (int dt = 0; dt < 2; dt++)
        GLDS16(vsrc + (size_t)dt * 32 * T + kc * 16, &KV[0][4096 + (kc * 2 + dt) * 512]);
  }

  for (int t0 = 0; t0 < T; t0 += 64) {
    int buf = (t0 >> 6) & 1;
    __syncthreads();  // staging of `buf` complete (vmcnt drained at barrier)

    // prefetch next tile into buf^1 (in flight during compute)
    if (t0 + 64 < T) {
      if (wave == 0) {
        const __bf16* ks = ksrc + (size_t)(t0 + 64) * C3;
        for (int ct = 0; ct < 2; ct++)
          for (int c = 0; c < 4; c++)
            GLDS16(ks + (size_t)ct * 32 * C3 + c * 16, &KV[buf ^ 1][(ct * 4 + c) * 512]);
      } else {
        const __bf16* vs = vsrc + t0 + 64;
        for (int kc = 0; kc < 4; kc++)
          for (int dt = 0; dt < 2; dt++)
            GLDS16(vs + (size_t)dt * 32 * T + kc * 16,
                   &KV[buf ^ 1][4096 + (kc * 2 + dt) * 512]);
      }
    }

    const __bf16* Kb = &KV[buf][0];
    const __bf16* Vb = &KV[buf][4096];

    // S = Q K^T per ct (32 kv cols each), then P = exp2(S) -> Ps (same wave)
    for (int ct = 0; ct < 2; ct++) {
      f32x16 ss = {};
      for (int c = 0; c < 4; c++) {
        bf16x8 bk = *(const bf16x8*)&Kb[(ct * 4 + c) * 512 + lane * 8];
        ss = MFMA32(aq[c], bk, ss);
      }
#pragma unroll
      for (int reg = 0; reg < 16; reg++) {
        int dq = (reg & 3) + 8 * (reg >> 2);
        float p = __builtin_amdgcn_exp2f(ss[reg]);
        Ps[wave][wbase + ct * 1024 + dq * 8] = (__bf16)p;
      }
    }
    // no barrier: Ps wave-private; same-wave DS ordering

    // O += P V ; row sums via ones-B MFMA (reuses P A-frags)
    for (int kc = 0; kc < 4; kc++) {
      bf16x8 ap = *(const bf16x8*)&Ps[wave][rbase + kc * 512];
      ls = MFMA32(ap, ones, ls);
      bf16x8 bv0 = *(const bf16x8*)&Vb[(kc * 2 + 0) * 512 + lane * 8];
      bf16x8 bv1 = *(const bf16x8*)&Vb[(kc * 2 + 1) * 512 + lane * 8];
      o0 = MFMA32(ap, bv0, o0);
      o1 = MFMA32(ap, bv1, o1);
    }
  }

  // epilogue: normalize and store. C/D: col = dt*32 + l31, row = dq + 4*hw
  __bf16* obase = O + (size_t)(b * T + q0 + wave * 32 + 4 * hw) * 1024 + h * 64 + l31;
#pragma unroll
  for (int reg = 0; reg < 16; reg++) {
    int dq = (reg & 3) + 8 * (reg >> 2);
    float inv = 1.0f / ls[reg];
    obase[(size_t)dq * 1024] = (__bf16)(o0[reg] * inv);
    obase[(size_t)dq * 1024 + 32] = (__bf16)(o1[reg] * inv);
  }
}

// ---------------- launch ----------------
extern "C" void kernel_launch(void* const* d_in, const int* in_sizes, int n_in,
                              void* d_out, int out_size, void* d_ws, size_t ws_size,
                              hipStream_t stream) {
  const float* x = (const float*)d_in[0];      // [2,2048,1024]
  const float* W_qkv = (const float*)d_in[1];  // [1024,3072]
  const float* b_qkv = (const float*)d_in[2];  // [3072]
  const float* W_out = (const float*)d_in[3];  // [1024,1024]
  const float* b_out = (const float*)d_in[4];  // [1024]
  float* out = (float*)d_out;                  // [2,2048,1024] f32

  char* ws = (char*)d_ws;
  __bf16* WqkvT = (__bf16*)(ws);               // [3072][1024]  6 MB
  __bf16* WoT = (__bf16*)(ws + 6291456);       // [1024][1024]  2 MB
  __bf16* xb = (__bf16*)(ws + 8388608);        // [4096][1024]  8 MB
  __bf16* qkvb = (__bf16*)(ws + 16777216);     // [4096][3072] 24 MB
  __bf16* Vt = (__bf16*)(ws + 41943040);       // [2][16][64][2048] 8 MB
  __bf16* attnb = xb;  // xb dead after gemm1; reuse for attention output

  const float cs = 0.125f * 1.44269504089f;  // 1/sqrt(64) * log2(e)

  cvt_bf16_kernel<<<4096, 256, 0, stream>>>(x, xb, 1048576);
  transpose_w_kernel<<<dim3(128, 32), 256, 0, stream>>>(W_qkv, WqkvT, W_out, WoT);
  gemm_kernel<false, 128><<<dim3(32, 24), 256, 0, stream>>>(xb, WqkvT, b_qkv, qkvb, 3072,
                                                            1024, cs);
  transpose_v_kernel<<<dim3(32, 16, 2), 256, 0, stream>>>(qkvb, Vt);
  attn_kernel<<<dim3(32, 16, 2), 128, 0, stream>>>(qkvb, Vt, attnb);
  gemm_kernel<true, 64><<<dim3(32, 16), 256, 0, stream>>>(attnb, WoT, b_out, out, 1024,
                                                          0, 1.0f);
}